// Round 1
// 357.732 us; speedup vs baseline: 1.0119x; 1.0119x over previous
//
#include <hip/hip_runtime.h>

#define B_ROWS 16384
#define C_DIM  2048
#define BLK    512               // 8 waves
#define NWAVE  (BLK / 64)
#define RPW    4                 // rows per wave (one batch, no outer loop)
#define RPB    (NWAVE * RPW)     // 32 rows per block -> grid.x = 512, grid.y = 3
#define NACC   5                 // aff0, aff1, aff2, cls0, cls1
#define NCHUNK (C_DIM / 256)     // 8 chunks of 64 lanes x 4 cols

#define DPP_ADD(v, ctrl, rmask) \
  v += __int_as_float(__builtin_amdgcn_update_dpp(0, __float_as_int(v), (ctrl), (rmask), 0xf, false))

// Kernel 1: wave-private row processing. Weights live in LDS (transposed to
// 5 x float4[512], stride-16B conflict-free ds_read_b128). No barriers in the
// hot loop -> prefetched global loads are never drained by s_barrier waitcnts.
__global__ __launch_bounds__(BLK)
void maff_partial(const float* __restrict__ s_f,
                  const float* __restrict__ g_f,
                  const float* __restrict__ v_f,
                  const float* __restrict__ W_aff,
                  const float* __restrict__ W_cls,
                  float* __restrict__ ws)
{
  const int t    = threadIdx.x;
  const int lane = t & 63;
  const int wave = t >> 6;
  const int m    = blockIdx.y;
  const int row0 = blockIdx.x * RPB + wave * RPW;

  const float* f = (m == 0) ? s_f : (m == 1) ? g_f : v_f;

  // ---- LDS weights: W[j][quad] = weights of output j for column quad ----
  __shared__ float4 W[NACC][BLK];   // 40 KB
  {
    // thread t builds column quad t (cols 4t..4t+3). All loads 16B-aligned.
    const float4* pa = (const float4*)(W_aff + ((size_t)m * C_DIM + t * 4) * 3);
    float4 a0 = pa[0], a1 = pa[1], a2 = pa[2];
    const float4* pc = (const float4*)(W_cls + ((size_t)m * C_DIM + t * 4) * 2);
    float4 q0 = pc[0], q1 = pc[1];
    W[0][t] = make_float4(a0.x, a0.w, a1.z, a2.y);   // aff col 0
    W[1][t] = make_float4(a0.y, a1.x, a1.w, a2.z);   // aff col 1
    W[2][t] = make_float4(a0.z, a1.y, a2.x, a2.w);   // aff col 2
    W[3][t] = make_float4(q0.x, q0.z, q1.x, q1.z);   // cls col 0
    W[4][t] = make_float4(q0.y, q0.w, q1.y, q1.w);   // cls col 1
  }
  __syncthreads();   // the only barrier in this kernel

  const float4* wp = &W[0][lane];                       // + j*BLK + ch*64 (imm offsets)
  const float*  fb = f + (size_t)row0 * C_DIM + lane * 4;

  float acc[RPW][NACC];
#pragma unroll
  for (int r = 0; r < RPW; ++r)
#pragma unroll
    for (int j = 0; j < NACC; ++j)
      acc[r][j] = 0.f;

  // ---- main: 8 chunks x 4 rows; 32 independent float4 streams per wave ----
#pragma unroll
  for (int ch = 0; ch < NCHUNK; ++ch) {
    float4 x[RPW];
#pragma unroll
    for (int r = 0; r < RPW; ++r)
      x[r] = *(const float4*)(fb + (size_t)r * C_DIM + ch * 256);

    float4 wv[NACC];
#pragma unroll
    for (int j = 0; j < NACC; ++j)
      wv[j] = wp[j * BLK + ch * 64];

#pragma unroll
    for (int r = 0; r < RPW; ++r)
#pragma unroll
      for (int j = 0; j < NACC; ++j)
        acc[r][j] = fmaf(x[r].w, wv[j].w,
                    fmaf(x[r].z, wv[j].z,
                    fmaf(x[r].y, wv[j].y,
                    fmaf(x[r].x, wv[j].x, acc[r][j]))));
  }

  // ---- one full-wave reduction per row (6 DPP steps per accumulator) ----
#pragma unroll
  for (int r = 0; r < RPW; ++r)
#pragma unroll
    for (int j = 0; j < NACC; ++j) {
      float v = acc[r][j];
      DPP_ADD(v, 0x111, 0xf);   // row_shr:1
      DPP_ADD(v, 0x112, 0xf);   // row_shr:2
      DPP_ADD(v, 0x114, 0xf);   // row_shr:4
      DPP_ADD(v, 0x118, 0xf);   // row_shr:8  -> lane 16k+15 = group sum
      DPP_ADD(v, 0x142, 0xa);   // row_bcast:15 -> lane 31 = sum(0..31), lane 63 = sum(32..63)
      DPP_ADD(v, 0x143, 0xc);   // row_bcast:31 -> lane 63 = full wave sum
      acc[r][j] = v;
    }

  if (lane == 63) {
#pragma unroll
    for (int r = 0; r < RPW; ++r)
#pragma unroll
      for (int j = 0; j < NACC; ++j)
        ws[(size_t)(m * NACC + j) * B_ROWS + row0 + r] = acc[r][j];
  }
}

// Kernel 2: per-row epilogue. 15 coalesced reads, two softmaxes, float2 store.
__global__ __launch_bounds__(256)
void maff_epilogue(const float* __restrict__ ws,
                   const float* __restrict__ b_aff,
                   const float* __restrict__ b_cls,
                   float* __restrict__ out)
{
  const int row = blockIdx.x * 256 + threadIdx.x;

  float P[3][NACC];
#pragma unroll
  for (int m = 0; m < 3; ++m)
#pragma unroll
    for (int j = 0; j < NACC; ++j)
      P[m][j] = ws[(m * NACC + j) * B_ROWS + row];

  float A0 = P[0][0] + P[1][0] + P[2][0] + b_aff[0];
  float A1 = P[0][1] + P[1][1] + P[2][1] + b_aff[1];
  float A2 = P[0][2] + P[1][2] + P[2][2] + b_aff[2];

  float mx = fmaxf(A0, fmaxf(A1, A2));
  float e0 = __expf(A0 - mx), e1 = __expf(A1 - mx), e2 = __expf(A2 - mx);
  float inv = 1.0f / (e0 + e1 + e2);
  float t0 = e0 * inv, t1 = e1 * inv, t2 = e2 * inv;

  float L0 = t0 * P[0][3] + t1 * P[1][3] + t2 * P[2][3] + b_cls[0];
  float L1 = t0 * P[0][4] + t1 * P[1][4] + t2 * P[2][4] + b_cls[1];
  float mm = fmaxf(L0, L1);
  float x0 = __expf(L0 - mm), x1 = __expf(L1 - mm);
  float is = 1.0f / (x0 + x1);

  *(float2*)(out + (size_t)row * 2) = make_float2(x0 * is, x1 * is);
}

extern "C" void kernel_launch(void* const* d_in, const int* in_sizes, int n_in,
                              void* d_out, int out_size, void* d_ws, size_t ws_size,
                              hipStream_t stream) {
  const float* s_f   = (const float*)d_in[0];
  const float* g_f   = (const float*)d_in[1];
  const float* v_f   = (const float*)d_in[2];
  const float* W_aff = (const float*)d_in[3];
  const float* b_aff = (const float*)d_in[4];
  const float* W_cls = (const float*)d_in[5];
  const float* b_cls = (const float*)d_in[6];
  float* out = (float*)d_out;
  float* ws  = (float*)d_ws;   // 15 * B * 4 = 983 KB

  dim3 grid1(B_ROWS / RPB, 3);   // 512 x 3 = 1536 blocks, 512 thr each
  maff_partial<<<grid1, dim3(BLK), 0, stream>>>(s_f, g_f, v_f, W_aff, W_cls, ws);

  dim3 grid2(B_ROWS / 256);      // 64 blocks
  maff_epilogue<<<grid2, dim3(256), 0, stream>>>(ws, b_aff, b_cls, out);
}

// Round 2
// 353.665 us; speedup vs baseline: 1.0235x; 1.0115x over previous
//
#include <hip/hip_runtime.h>

#define B_ROWS 16384
#define C_DIM  2048
#define BLK    512               // 8 waves
#define NWAVE  (BLK / 64)
#define RPW    2                 // rows per wave
#define RPB    (NWAVE * RPW)     // 16 rows per block -> grid.x = 1024, grid.y = 3
#define NACC   5                 // aff0, aff1, aff2, cls0, cls1
#define NCHUNK (C_DIM / 256)     // 8 chunks of 64 lanes x 4 cols

#define DPP_ADD(v, ctrl, rmask) \
  v += __int_as_float(__builtin_amdgcn_update_dpp(0, __float_as_int(v), (ctrl), (rmask), 0xf, false))

// Kernel 1: wave-private rows, ALL 16 global float4 loads staged into registers
// before any compute -> 16 KB in flight per wave, staged vmcnt waits, no
// per-chunk memory round-trips on the critical path.
__global__ __launch_bounds__(BLK)
void maff_partial(const float* __restrict__ s_f,
                  const float* __restrict__ g_f,
                  const float* __restrict__ v_f,
                  const float* __restrict__ W_aff,
                  const float* __restrict__ W_cls,
                  float* __restrict__ ws)
{
  const int t    = threadIdx.x;
  const int lane = t & 63;
  const int wave = t >> 6;
  const int m    = blockIdx.y;
  const int row0 = blockIdx.x * RPB + wave * RPW;

  const float* f = (m == 0) ? s_f : (m == 1) ? g_f : v_f;

  // ---- LDS weights: W[j][quad] = weights of output j for column quad ----
  __shared__ float4 W[NACC][BLK];   // 40 KB
  {
    const float4* pa = (const float4*)(W_aff + ((size_t)m * C_DIM + t * 4) * 3);
    float4 a0 = pa[0], a1 = pa[1], a2 = pa[2];
    const float4* pc = (const float4*)(W_cls + ((size_t)m * C_DIM + t * 4) * 2);
    float4 q0 = pc[0], q1 = pc[1];
    W[0][t] = make_float4(a0.x, a0.w, a1.z, a2.y);   // aff col 0
    W[1][t] = make_float4(a0.y, a1.x, a1.w, a2.z);   // aff col 1
    W[2][t] = make_float4(a0.z, a1.y, a2.x, a2.w);   // aff col 2
    W[3][t] = make_float4(q0.x, q0.z, q1.x, q1.z);   // cls col 0
    W[4][t] = make_float4(q0.y, q0.w, q1.y, q1.w);   // cls col 1
  }
  __syncthreads();   // the only barrier

  const float4* wp = &W[0][lane];
  const float*  fb0 = f + (size_t)row0 * C_DIM + lane * 4;
  const float*  fb1 = fb0 + C_DIM;

  // ---- stage ALL loads: 8 chunks x 2 rows = 16 float4 (64 VGPRs) ----
  float4 x[NCHUNK][RPW];
#pragma unroll
  for (int ch = 0; ch < NCHUNK; ++ch) {
    x[ch][0] = *(const float4*)(fb0 + ch * 256);
    x[ch][1] = *(const float4*)(fb1 + ch * 256);
  }

  float acc[RPW][NACC];
#pragma unroll
  for (int r = 0; r < RPW; ++r)
#pragma unroll
    for (int j = 0; j < NACC; ++j)
      acc[r][j] = 0.f;

  // ---- compute: weights re-read from LDS per chunk (BW is ample) ----
#pragma unroll
  for (int ch = 0; ch < NCHUNK; ++ch) {
    float4 wv[NACC];
#pragma unroll
    for (int j = 0; j < NACC; ++j)
      wv[j] = wp[j * BLK + ch * 64];
#pragma unroll
    for (int r = 0; r < RPW; ++r)
#pragma unroll
      for (int j = 0; j < NACC; ++j)
        acc[r][j] = fmaf(x[ch][r].w, wv[j].w,
                    fmaf(x[ch][r].z, wv[j].z,
                    fmaf(x[ch][r].y, wv[j].y,
                    fmaf(x[ch][r].x, wv[j].x, acc[r][j]))));
  }

  // ---- one full-wave reduction per row (6 DPP steps per accumulator) ----
#pragma unroll
  for (int r = 0; r < RPW; ++r)
#pragma unroll
    for (int j = 0; j < NACC; ++j) {
      float v = acc[r][j];
      DPP_ADD(v, 0x111, 0xf);   // row_shr:1
      DPP_ADD(v, 0x112, 0xf);   // row_shr:2
      DPP_ADD(v, 0x114, 0xf);   // row_shr:4
      DPP_ADD(v, 0x118, 0xf);   // row_shr:8  -> lane 16k+15 = group sum
      DPP_ADD(v, 0x142, 0xa);   // row_bcast:15
      DPP_ADD(v, 0x143, 0xc);   // row_bcast:31 -> lane 63 = full wave sum
      acc[r][j] = v;
    }

  if (lane == 63) {
#pragma unroll
    for (int r = 0; r < RPW; ++r)
#pragma unroll
      for (int j = 0; j < NACC; ++j)
        ws[(size_t)(m * NACC + j) * B_ROWS + row0 + r] = acc[r][j];
  }
}

// Kernel 2: per-row epilogue. 15 coalesced reads, two softmaxes, float2 store.
__global__ __launch_bounds__(256)
void maff_epilogue(const float* __restrict__ ws,
                   const float* __restrict__ b_aff,
                   const float* __restrict__ b_cls,
                   float* __restrict__ out)
{
  const int row = blockIdx.x * 256 + threadIdx.x;

  float P[3][NACC];
#pragma unroll
  for (int m = 0; m < 3; ++m)
#pragma unroll
    for (int j = 0; j < NACC; ++j)
      P[m][j] = ws[(m * NACC + j) * B_ROWS + row];

  float A0 = P[0][0] + P[1][0] + P[2][0] + b_aff[0];
  float A1 = P[0][1] + P[1][1] + P[2][1] + b_aff[1];
  float A2 = P[0][2] + P[1][2] + P[2][2] + b_aff[2];

  float mx = fmaxf(A0, fmaxf(A1, A2));
  float e0 = __expf(A0 - mx), e1 = __expf(A1 - mx), e2 = __expf(A2 - mx);
  float inv = 1.0f / (e0 + e1 + e2);
  float t0 = e0 * inv, t1 = e1 * inv, t2 = e2 * inv;

  float L0 = t0 * P[0][3] + t1 * P[1][3] + t2 * P[2][3] + b_cls[0];
  float L1 = t0 * P[0][4] + t1 * P[1][4] + t2 * P[2][4] + b_cls[1];
  float mm = fmaxf(L0, L1);
  float x0 = __expf(L0 - mm), x1 = __expf(L1 - mm);
  float is = 1.0f / (x0 + x1);

  *(float2*)(out + (size_t)row * 2) = make_float2(x0 * is, x1 * is);
}

extern "C" void kernel_launch(void* const* d_in, const int* in_sizes, int n_in,
                              void* d_out, int out_size, void* d_ws, size_t ws_size,
                              hipStream_t stream) {
  const float* s_f   = (const float*)d_in[0];
  const float* g_f   = (const float*)d_in[1];
  const float* v_f   = (const float*)d_in[2];
  const float* W_aff = (const float*)d_in[3];
  const float* b_aff = (const float*)d_in[4];
  const float* W_cls = (const float*)d_in[5];
  const float* b_cls = (const float*)d_in[6];
  float* out = (float*)d_out;
  float* ws  = (float*)d_ws;   // 15 * B * 4 = 983 KB

  dim3 grid1(B_ROWS / RPB, 3);   // 1024 x 3 = 3072 blocks, 512 thr each
  maff_partial<<<grid1, dim3(BLK), 0, stream>>>(s_f, g_f, v_f, W_aff, W_cls, ws);

  dim3 grid2(B_ROWS / 256);      // 64 blocks
  maff_epilogue<<<grid2, dim3(256), 0, stream>>>(ws, b_aff, b_cls, out);
}

// Round 4
// 350.328 us; speedup vs baseline: 1.0333x; 1.0095x over previous
//
#include <hip/hip_runtime.h>

#define B_ROWS 16384
#define C_DIM  2048
#define BLK    512               // 8 waves
#define NWAVE  (BLK / 64)
#define RPW    2                 // rows per wave
#define RPB    (NWAVE * RPW)     // 16 rows per block -> grid.x = 1024, grid.y = 3
#define NACC   5                 // aff0, aff1, aff2, cls0, cls1
#define NCHUNK (C_DIM / 256)     // 8 chunks of 64 lanes x 4 cols

#define DPP_ADD(v, ctrl, rmask) \
  v += __int_as_float(__builtin_amdgcn_update_dpp(0, __float_as_int(v), (ctrl), (rmask), 0xf, false))

// Kernel 1: wave-private rows. Weight staging + barrier happen FIRST; then all
// 16 global float4 data loads are issued back-to-back and pinned by a
// memory-clobber asm (loads cannot be sunk/rematerialized across it). The
// compute loop then drains them with staged vmcnt(N) waits per chunk: chunk-0
// compute starts after ~1 load latency while 14 loads keep flying.
// __launch_bounds__(512,4) budgets ~128 VGPRs so the 16 staged float4
// destinations stay live (R2 showed the allocator otherwise collapses to 32
// VGPRs / ~2 loads in flight -> 3.2 TB/s latency-bound plateau).
__global__ __launch_bounds__(BLK, 4)
void maff_partial(const float* __restrict__ s_f,
                  const float* __restrict__ g_f,
                  const float* __restrict__ v_f,
                  const float* __restrict__ W_aff,
                  const float* __restrict__ W_cls,
                  float* __restrict__ ws)
{
  const int t    = threadIdx.x;
  const int lane = t & 63;
  const int wave = t >> 6;
  const int m    = blockIdx.y;
  const int row0 = blockIdx.x * RPB + wave * RPW;

  const float* f = (m == 0) ? s_f : (m == 1) ? g_f : v_f;

  // ---- LDS weights: W[j][quad] = weights of output j for column quad ----
  __shared__ float4 W[NACC][BLK];   // 40 KB
  {
    const float4* pa = (const float4*)(W_aff + ((size_t)m * C_DIM + t * 4) * 3);
    float4 a0 = pa[0], a1 = pa[1], a2 = pa[2];
    const float4* pc = (const float4*)(W_cls + ((size_t)m * C_DIM + t * 4) * 2);
    float4 q0 = pc[0], q1 = pc[1];
    W[0][t] = make_float4(a0.x, a0.w, a1.z, a2.y);   // aff col 0
    W[1][t] = make_float4(a0.y, a1.x, a1.w, a2.z);   // aff col 1
    W[2][t] = make_float4(a0.z, a1.y, a2.x, a2.w);   // aff col 2
    W[3][t] = make_float4(q0.x, q0.z, q1.x, q1.z);   // cls col 0
    W[4][t] = make_float4(q0.y, q0.w, q1.y, q1.w);   // cls col 1
  }
  __syncthreads();   // weights visible; data loads issue after this barrier

  const float* fb0 = f + (size_t)row0 * C_DIM + lane * 4;
  const float* fb1 = fb0 + C_DIM;

  // ---- issue ALL data loads back-to-back: 8 chunks x 2 rows = 16 float4 ----
  float4 x[NCHUNK][RPW];
#pragma unroll
  for (int ch = 0; ch < NCHUNK; ++ch) {
    x[ch][0] = *(const float4*)(fb0 + ch * 256);
    x[ch][1] = *(const float4*)(fb1 + ch * 256);
  }
  // Loads may not be sunk below this point.
  asm volatile("" ::: "memory");

  const float4* wp = &W[0][lane];

  float acc[RPW][NACC];
#pragma unroll
  for (int r = 0; r < RPW; ++r)
#pragma unroll
    for (int j = 0; j < NACC; ++j)
      acc[r][j] = 0.f;

  // ---- compute: staged vmcnt drains, weights broadcast from LDS ----
#pragma unroll
  for (int ch = 0; ch < NCHUNK; ++ch) {
    float4 wv[NACC];
#pragma unroll
    for (int j = 0; j < NACC; ++j)
      wv[j] = wp[j * BLK + ch * 64];
#pragma unroll
    for (int r = 0; r < RPW; ++r)
#pragma unroll
      for (int j = 0; j < NACC; ++j)
        acc[r][j] = fmaf(x[ch][r].w, wv[j].w,
                    fmaf(x[ch][r].z, wv[j].z,
                    fmaf(x[ch][r].y, wv[j].y,
                    fmaf(x[ch][r].x, wv[j].x, acc[r][j]))));
  }

  // ---- one full-wave reduction per row (6 DPP steps per accumulator) ----
#pragma unroll
  for (int r = 0; r < RPW; ++r)
#pragma unroll
    for (int j = 0; j < NACC; ++j) {
      float v = acc[r][j];
      DPP_ADD(v, 0x111, 0xf);   // row_shr:1
      DPP_ADD(v, 0x112, 0xf);   // row_shr:2
      DPP_ADD(v, 0x114, 0xf);   // row_shr:4
      DPP_ADD(v, 0x118, 0xf);   // row_shr:8  -> lane 16k+15 = group sum
      DPP_ADD(v, 0x142, 0xa);   // row_bcast:15
      DPP_ADD(v, 0x143, 0xc);   // row_bcast:31 -> lane 63 = full wave sum
      acc[r][j] = v;
    }

  if (lane == 63) {
#pragma unroll
    for (int r = 0; r < RPW; ++r)
#pragma unroll
      for (int j = 0; j < NACC; ++j)
        ws[(size_t)(m * NACC + j) * B_ROWS + row0 + r] = acc[r][j];
  }
}

// Kernel 2: per-row epilogue. 15 coalesced reads, two softmaxes, float2 store.
__global__ __launch_bounds__(256)
void maff_epilogue(const float* __restrict__ ws,
                   const float* __restrict__ b_aff,
                   const float* __restrict__ b_cls,
                   float* __restrict__ out)
{
  const int row = blockIdx.x * 256 + threadIdx.x;

  float P[3][NACC];
#pragma unroll
  for (int m = 0; m < 3; ++m)
#pragma unroll
    for (int j = 0; j < NACC; ++j)
      P[m][j] = ws[(m * NACC + j) * B_ROWS + row];

  float A0 = P[0][0] + P[1][0] + P[2][0] + b_aff[0];
  float A1 = P[0][1] + P[1][1] + P[2][1] + b_aff[1];
  float A2 = P[0][2] + P[1][2] + P[2][2] + b_aff[2];

  float mx = fmaxf(A0, fmaxf(A1, A2));
  float e0 = __expf(A0 - mx), e1 = __expf(A1 - mx), e2 = __expf(A2 - mx);
  float inv = 1.0f / (e0 + e1 + e2);
  float t0 = e0 * inv, t1 = e1 * inv, t2 = e2 * inv;

  float L0 = t0 * P[0][3] + t1 * P[1][3] + t2 * P[2][3] + b_cls[0];
  float L1 = t0 * P[0][4] + t1 * P[1][4] + t2 * P[2][4] + b_cls[1];
  float mm = fmaxf(L0, L1);
  float x0 = __expf(L0 - mm), x1 = __expf(L1 - mm);
  float is = 1.0f / (x0 + x1);

  *(float2*)(out + (size_t)row * 2) = make_float2(x0 * is, x1 * is);
}

extern "C" void kernel_launch(void* const* d_in, const int* in_sizes, int n_in,
                              void* d_out, int out_size, void* d_ws, size_t ws_size,
                              hipStream_t stream) {
  const float* s_f   = (const float*)d_in[0];
  const float* g_f   = (const float*)d_in[1];
  const float* v_f   = (const float*)d_in[2];
  const float* W_aff = (const float*)d_in[3];
  const float* b_aff = (const float*)d_in[4];
  const float* W_cls = (const float*)d_in[5];
  const float* b_cls = (const float*)d_in[6];
  float* out = (float*)d_out;
  float* ws  = (float*)d_ws;   // 15 * B * 4 = 983 KB

  dim3 grid1(B_ROWS / RPB, 3);   // 1024 x 3 = 3072 blocks, 512 thr each
  maff_partial<<<grid1, dim3(BLK), 0, stream>>>(s_f, g_f, v_f, W_aff, W_cls, ws);

  dim3 grid2(B_ROWS / 256);      // 64 blocks
  maff_epilogue<<<grid2, dim3(256), 0, stream>>>(ws, b_aff, b_cls, out);
}